// Round 9
// baseline (259.456 us; speedup 1.0000x reference)
//
#include <hip/hip_runtime.h>
#include <hip/hip_bf16.h>
#include <stdint.h>

#define TW_N 2047
#define BATCH 8
#define T_LEN 65536
#define NCH 64
#define HID 512
#define NWIN (BATCH * TW_N) /* 16376 */

typedef unsigned short ushortT;

// ---------- bf16 pack helpers (used only for the GEMM operands in ws) ----------
__device__ __forceinline__ ushortT f2b(float f) {
  union { float f; uint32_t i; } v; v.f = f;
  uint32_t r = v.i + 0x7fffu + ((v.i >> 16) & 1u);
  return (ushortT)(r >> 16);
}
__device__ __forceinline__ uint32_t pk2(float lo, float hi) {
  return (uint32_t)f2b(lo) | ((uint32_t)f2b(hi) << 16);
}

// ---------- compile-time DFT twiddles: cos/sin(2*pi*m/64) ----------
constexpr float CQ[17] = {
  1.0f, 0.9951847267f, 0.9807852804f, 0.9569403357f, 0.9238795325f,
  0.8819212643f, 0.8314696123f, 0.7730104534f, 0.7071067812f, 0.6343932842f,
  0.5555702330f, 0.4713967368f, 0.3826834324f, 0.2902846773f, 0.1950903220f,
  0.0980171403f, 0.0f };
constexpr float cos64(int m) {
  m &= 63;
  return (m <= 16) ? CQ[m] : (m < 32) ? -CQ[32 - m] : (m < 48) ? -CQ[m - 32] : CQ[64 - m];
}
constexpr float sin64(int m) { return cos64(m - 16); }
struct TwTab { float c[24][32]; float s[24][32]; };
constexpr TwTab make_tab() {
  TwTab t{};
  for (int i = 0; i < 24; ++i)
    for (int j = 0; j < 32; ++j) {
      int m = ((i + 1) * j) & 63;
      t.c[i][j] = cos64(m);
      t.s[i][j] = sin64(m);
    }
  return t;
}
constexpr TwTab TT = make_tab();

// ---------- K0: out[b,0,:] = marker (fp32 copy), 16 blocks ----------
__global__ __launch_bounds__(256) void marker_kernel(
    const float* __restrict__ marker, float* __restrict__ out)
{
  const int idx = blockIdx.x * 256 + threadIdx.x;   // 4096 = 8*512
  out[(size_t)(idx >> 9) * (2048 * 512) + (idx & 511)] = marker[idx & 511];
}

// ---------- K1: windows -> 7 feats -> per-channel embed -> flat bf16 (ws) ----------
// one wave per window, lane = channel; signal fp32
__global__ __launch_bounds__(256) void feat_embed_kernel(
    const float* __restrict__ sig, const float* __restrict__ chw,
    const float* __restrict__ chb, ushortT* __restrict__ flatB)
{
  const int wv = threadIdx.x >> 6;
  const int c = threadIdx.x & 63;
  const int w = blockIdx.x * 4 + wv;       // < 16376 (4094 blocks * 4 waves exactly)
  const int b = w / TW_N;
  const int tw = w - b * TW_N;
  const size_t base = ((size_t)(b * T_LEN + tw * 32)) * NCH + c;

  float x[64];
#pragma unroll
  for (int t = 0; t < 64; ++t) x[t] = sig[base + (size_t)t * NCH];

  float sum = 0.f, sumsq = 0.f;
#pragma unroll
  for (int t = 0; t < 64; ++t) { sum += x[t]; sumsq = fmaf(x[t], x[t], sumsq); }

  float e[32], o[32];
#pragma unroll
  for (int t = 0; t < 32; ++t) { e[t] = x[t] + x[t + 32]; o[t] = x[t] - x[t + 32]; }

  // X_k = sum_{t<32} (k even ? e : o)[t] * w^{kt},  k = 1..24
  float b1 = 0.f, b2 = 0.f, b3 = 0.f, b4 = 0.f;
#pragma unroll
  for (int i = 0; i < 24; ++i) {
    const int k = i + 1;
    float re = 0.f, im = 0.f;
#pragma unroll
    for (int t = 0; t < 32; ++t) {
      const float v = (k & 1) ? o[t] : e[t];
      re = fmaf(v, TT.c[i][t], re);
      im = fmaf(v, TT.s[i][t], im);
    }
    const float mag = sqrtf(fmaf(re, re, im * im));
    if (k == 1) b1 += mag;
    else if (k < 4) b2 += mag;
    else if (k < 8) b3 += mag;
    else b4 += mag;
  }

  const float mean = sum * (1.f / 64.f);
  const float var = (sumsq - sum * sum * (1.f / 64.f)) * (1.f / 63.f);
  const float sd = sqrtf(fmaxf(var, 0.f));

  float feats[7];
  feats[0] = 0.f;               // band (0.5,4): no bins at 4 Hz resolution
  feats[1] = b1;
  feats[2] = b2 * 0.5f;
  feats[3] = b3 * 0.25f;
  feats[4] = b4 * (1.f / 17.f);
  feats[5] = mean;
  feats[6] = sd;

  const float* wr = chw + c * 56;
  float emb[8];
#pragma unroll
  for (int p = 0; p < 8; ++p) emb[p] = chb[c * 8 + p];
#pragma unroll
  for (int f = 1; f < 7; ++f) {
    const float fv = feats[f];
#pragma unroll
    for (int p = 0; p < 8; ++p) emb[p] = fmaf(fv, wr[f * 8 + p], emb[p]);
  }

  uint32_t pka[4];
#pragma unroll
  for (int q = 0; q < 4; ++q) pka[q] = pk2(emb[2 * q], emb[2 * q + 1]);
  *(uint4*)(flatB + (size_t)w * HID + c * 8) = make_uint4(pka[0], pka[1], pka[2], pka[3]);
}

// ---------- K2: z = flat @ mix_w^T + PE(inline), bf16 MFMA GEMM, fp32 out ----------
typedef __attribute__((ext_vector_type(8))) short short8;
typedef __attribute__((ext_vector_type(4))) float f32x4;

__global__ __launch_bounds__(256) void mix_gemm_kernel(
    const ushortT* __restrict__ A,    // flatB [16376][512] bf16 (ws)
    const float* __restrict__ Bw,     // mix_w [512][512] fp32 (input)
    float* __restrict__ out)
{
  __shared__ ushortT As[128 * 32];
  __shared__ ushortT Bs[128 * 32];

  const int tid = threadIdx.x;
  const int lane = tid & 63;
  const int wv = tid >> 6;
  const int wm = wv >> 1, wn = wv & 1;
  const int fr = lane & 15;
  const int fq = lane >> 4;

  const int n0 = blockIdx.x * 128;   // 4 col-blocks
  const int m0 = blockIdx.y * 128;   // 128 row-blocks

  const int srow = tid >> 2;         // staging: 64 rows per pass
  const int sko = (tid & 3) << 3;    // k-offset in elements (0,8,16,24)

  f32x4 acc[4][4];
#pragma unroll
  for (int i = 0; i < 4; ++i)
#pragma unroll
    for (int j = 0; j < 4; ++j) acc[i][j] = (f32x4){0.f, 0.f, 0.f, 0.f};

  uint4 ra[2];
  float4 rbf[2][2];
#pragma unroll
  for (int p = 0; p < 2; ++p) {
    int am = m0 + p * 64 + srow; am = am < (NWIN - 1) ? am : (NWIN - 1);
    ra[p] = *(const uint4*)(A + (size_t)am * HID + sko);
    const float* src = Bw + (size_t)(n0 + p * 64 + srow) * HID + sko;
    rbf[p][0] = *(const float4*)src;
    rbf[p][1] = *(const float4*)(src + 4);
  }

  for (int kt = 0; kt < 16; ++kt) {
#pragma unroll
    for (int p = 0; p < 2; ++p) {
      *(uint4*)&As[(p * 64 + srow) * 32 + sko] = ra[p];
      uint4 bb;
      bb.x = pk2(rbf[p][0].x, rbf[p][0].y);
      bb.y = pk2(rbf[p][0].z, rbf[p][0].w);
      bb.z = pk2(rbf[p][1].x, rbf[p][1].y);
      bb.w = pk2(rbf[p][1].z, rbf[p][1].w);
      *(uint4*)&Bs[(p * 64 + srow) * 32 + sko] = bb;
    }
    __syncthreads();
    if (kt < 15) {
      const int k0 = (kt + 1) * 32;
#pragma unroll
      for (int p = 0; p < 2; ++p) {
        int am = m0 + p * 64 + srow; am = am < (NWIN - 1) ? am : (NWIN - 1);
        ra[p] = *(const uint4*)(A + (size_t)am * HID + k0 + sko);
        const float* src = Bw + (size_t)(n0 + p * 64 + srow) * HID + k0 + sko;
        rbf[p][0] = *(const float4*)src;
        rbf[p][1] = *(const float4*)(src + 4);
      }
    }
    short8 af[4], bf[4];
#pragma unroll
    for (int mt = 0; mt < 4; ++mt)
      af[mt] = *(const short8*)&As[(wm * 64 + mt * 16 + fr) * 32 + fq * 8];
#pragma unroll
    for (int nt = 0; nt < 4; ++nt)
      bf[nt] = *(const short8*)&Bs[(wn * 64 + nt * 16 + fr) * 32 + fq * 8];
#pragma unroll
    for (int mt = 0; mt < 4; ++mt)
#pragma unroll
      for (int nt = 0; nt < 4; ++nt)
        acc[mt][nt] = __builtin_amdgcn_mfma_f32_16x16x32_bf16(af[mt], bf[nt], acc[mt][nt], 0, 0, 0);
    __syncthreads();
  }

  // epilogue (fp32 out): C/D layout col(n)=lane&15, row(m)=(lane>>4)*4+reg.
  // PE inline: pe[tw][d] = (d odd ? cos : sin)(tw * exp(-ln(1e4)/256 * (d>>1)))
#pragma unroll
  for (int nt = 0; nt < 4; ++nt) {
    const int ng = n0 + wn * 64 + nt * 16 + fr;
    const float dv = __expf(-0.03597789208f * (float)(ng >> 1));
    const bool odd = (ng & 1);
#pragma unroll
    for (int mt = 0; mt < 4; ++mt) {
#pragma unroll
      for (int r = 0; r < 4; ++r) {
        const int mg = m0 + wm * 64 + mt * 16 + fq * 4 + r;
        if (mg < NWIN) {
          const int bb = mg / TW_N;
          const int tw = mg - bb * TW_N;
          const float ang = (float)tw * dv;
          const float pev = odd ? __cosf(ang) : __sinf(ang);
          out[((size_t)(bb * 2048 + 1 + tw)) * HID + ng] = acc[mt][nt][r] + pev;
        }
      }
    }
  }
}

extern "C" void kernel_launch(void* const* d_in, const int* in_sizes, int n_in,
                              void* d_out, int out_size, void* d_ws, size_t ws_size,
                              hipStream_t stream)
{
  const float* sig = (const float*)d_in[0];
  const float* chw = (const float*)d_in[1];
  const float* chb = (const float*)d_in[2];
  const float* mxw = (const float*)d_in[3];
  const float* mkr = (const float*)d_in[4];
  float* out = (float*)d_out;

  ushortT* flatB = (ushortT*)d_ws;   // 16,769,024 B — only ws use

  hipLaunchKernelGGL(marker_kernel, dim3(16), dim3(256), 0, stream, mkr, out);
  hipLaunchKernelGGL(feat_embed_kernel, dim3(4094), dim3(256), 0, stream, sig, chw, chb, flatB);
  hipLaunchKernelGGL(mix_gemm_kernel, dim3(4, 128), dim3(256), 0, stream, flatB, mxw, out);
}